// Round 10
// baseline (85.258 us; speedup 1.0000x reference)
//
#include <hip/hip_runtime.h>

// out[b,n] = relu( sum_d x[b, idx[n,d]] * w[n,d] )
//   x: (B=256, N=16384) f32, w: (N,32) f32, idx: (N,32) i32, out: (B,N) f32
//
// R10: R9 + software pipelining of the global side against the DS side:
//   - iter-0 pw loads issued BEFORE LDS staging (latency hides under staging)
//   - double-buffered qd prefetch: iter i+1's 16 pw loads in flight while
//     iter i's 32 random ds_read_b64 + pk_fma execute.
// Structure: block = (quad of 4 b-rows) x (n-split of 4096); quad j-image
// packed h2 in 128 KiB LDS; __launch_bounds__(1024,4) = 16 waves/CU.

#define NB   16384
#define DEG  32

typedef __fp16 hp2 __attribute__((ext_vector_type(2)));  // cvt_pkrtz result type

__device__ __forceinline__ unsigned pk16(float a, float b) {
    return __builtin_bit_cast(unsigned, (hp2)__builtin_amdgcn_cvt_pkrtz(a, b));
}

__global__ __launch_bounds__(256) void prep_pw_kernel(
    const int* __restrict__ idx, const float* __restrict__ w,
    uint2* __restrict__ pw) {
    __shared__ int   idx_s[64][33];
    __shared__ float w_s[64][33];
    const int t  = threadIdx.x;
    const int nb = (int)blockIdx.x * 64;

    const int4*   src  = (const int4*)(idx + (size_t)nb * DEG);
    const float4* srcw = (const float4*)(w   + (size_t)nb * DEG);
#pragma unroll
    for (int p = 0; p < 2; ++p) {
        const int e4 = t + 256 * p;              // int4 index 0..511, coalesced
        const int n0 = e4 >> 3;
        const int c0 = (e4 & 7) * 4;
        const int4 v = src[e4];
        idx_s[n0][c0 + 0] = v.x; idx_s[n0][c0 + 1] = v.y;
        idx_s[n0][c0 + 2] = v.z; idx_s[n0][c0 + 3] = v.w;
        const float4 f = srcw[e4];
        w_s[n0][c0 + 0] = f.x; w_s[n0][c0 + 1] = f.y;
        w_s[n0][c0 + 2] = f.z; w_s[n0][c0 + 3] = f.w;
    }
    __syncthreads();

    const int np    = t & 63;
    const int dbase = t >> 6;
#pragma unroll
    for (int k = 0; k < 4; ++k) {
        const int d2 = dbase * 4 + k;            // 0..15
        uint2 o;
        o.x = (unsigned)idx_s[np][2 * d2] | ((unsigned)idx_s[np][2 * d2 + 1] << 16);
        o.y = pk16(w_s[np][2 * d2], w_s[np][2 * d2 + 1]);
        pw[(size_t)d2 * NB + nb + np] = o;
    }
}

__global__ __launch_bounds__(1024, 4) void gather4_kernel(
    const float* __restrict__ x, const uint2* __restrict__ pw,
    float* __restrict__ out) {
    extern __shared__ uint2 lds[];               // 16384 uint2 = 128 KiB
    const int t  = threadIdx.x;
    const int q  = (int)blockIdx.x & 63;         // quad -> b = 4q..4q+3
    const int n0 = ((int)blockIdx.x >> 6) * 4096;
    const int b0 = 4 * q;

#define PREF(dst, ni)                                            \
    _Pragma("unroll")                                            \
    for (int d2 = 0; d2 < 16; ++d2) dst[d2] = pw[(size_t)d2 * NB + (ni)];

#define BODY(qd, ni)                                                        \
    {                                                                       \
        hp2 a01 = {0, 0}, a23 = {0, 0}, c01 = {0, 0}, c23 = {0, 0};         \
        _Pragma("unroll")                                                   \
        for (int d2 = 0; d2 < 8; ++d2) {                                    \
            const unsigned jp = qd[d2].x;                                   \
            const uint2 g0 = lds[jp & 0xffffu];                             \
            const uint2 g1 = lds[jp >> 16];                                 \
            const hp2 w2 = __builtin_bit_cast(hp2, qd[d2].y);               \
            const hp2 wlo = {w2.x, w2.x};                                   \
            const hp2 whi = {w2.y, w2.y};                                   \
            a01 += wlo * __builtin_bit_cast(hp2, g0.x);                     \
            a23 += wlo * __builtin_bit_cast(hp2, g0.y);                     \
            a01 += whi * __builtin_bit_cast(hp2, g1.x);                     \
            a23 += whi * __builtin_bit_cast(hp2, g1.y);                     \
        }                                                                   \
        _Pragma("unroll")                                                   \
        for (int d2 = 8; d2 < 16; ++d2) {                                   \
            const unsigned jp = qd[d2].x;                                   \
            const uint2 g0 = lds[jp & 0xffffu];                             \
            const uint2 g1 = lds[jp >> 16];                                 \
            const hp2 w2 = __builtin_bit_cast(hp2, qd[d2].y);               \
            const hp2 wlo = {w2.x, w2.x};                                   \
            const hp2 whi = {w2.y, w2.y};                                   \
            c01 += wlo * __builtin_bit_cast(hp2, g0.x);                     \
            c23 += wlo * __builtin_bit_cast(hp2, g0.y);                     \
            c01 += whi * __builtin_bit_cast(hp2, g1.x);                     \
            c23 += whi * __builtin_bit_cast(hp2, g1.y);                     \
        }                                                                   \
        const hp2 s01 = a01 + c01;                                          \
        const hp2 s23 = a23 + c23;                                          \
        out[(size_t)(b0 + 0) * NB + (ni)] = fmaxf((float)s01.x, 0.f);       \
        out[(size_t)(b0 + 1) * NB + (ni)] = fmaxf((float)s01.y, 0.f);       \
        out[(size_t)(b0 + 2) * NB + (ni)] = fmaxf((float)s23.x, 0.f);       \
        out[(size_t)(b0 + 3) * NB + (ni)] = fmaxf((float)s23.y, 0.f);       \
    }

    // Issue iter-0 pw loads first: their latency hides under staging+barrier.
    uint2 qa[16], qb[16];
    PREF(qa, n0 + t);

    // Stage quad j-image straight from x (coalesced float4 per row).
    const float* xr0 = x + (size_t)b0 * NB;
    const float* xr1 = xr0 + NB;
    const float* xr2 = xr1 + NB;
    const float* xr3 = xr2 + NB;
#pragma unroll
    for (int p = 0; p < 4; ++p) {
        const int j = 4 * (t + 1024 * p);
        const float4 r0 = *(const float4*)&xr0[j];
        const float4 r1 = *(const float4*)&xr1[j];
        const float4 r2 = *(const float4*)&xr2[j];
        const float4 r3 = *(const float4*)&xr3[j];
        uint4 w0, w1;
        w0.x = pk16(r0.x, r1.x); w0.y = pk16(r2.x, r3.x);
        w0.z = pk16(r0.y, r1.y); w0.w = pk16(r2.y, r3.y);
        w1.x = pk16(r0.z, r1.z); w1.y = pk16(r2.z, r3.z);
        w1.z = pk16(r0.w, r1.w); w1.w = pk16(r2.w, r3.w);
        *(uint4*)&lds[j]     = w0;
        *(uint4*)&lds[j + 2] = w1;
    }
    __syncthreads();

    // 4 n-iters, double-buffered: prefetch i+1's pw while consuming i.
    PREF(qb, n0 + t + 1024);
    BODY(qa, n0 + t);
    PREF(qa, n0 + t + 2048);
    BODY(qb, n0 + t + 1024);
    PREF(qb, n0 + t + 3072);
    BODY(qa, n0 + t + 2048);
    BODY(qb, n0 + t + 3072);

#undef PREF
#undef BODY
}

extern "C" void kernel_launch(void* const* d_in, const int* in_sizes, int n_in,
                              void* d_out, int out_size, void* d_ws, size_t ws_size,
                              hipStream_t stream) {
    const float* x   = (const float*)d_in[0];    // (B, N)
    const float* w   = (const float*)d_in[1];    // (N, DEG)
    const int*   idx = (const int*)d_in[2];      // (N, DEG)
    float* out = (float*)d_out;                  // (B, N)
    uint2* pw  = (uint2*)d_ws;                   // [16][N] = 2 MiB

    // allow 128 KiB dynamic LDS (idempotent; host-side, capture-safe)
    (void)hipFuncSetAttribute((const void*)gather4_kernel,
                              hipFuncAttributeMaxDynamicSharedMemorySize, 131072);

    prep_pw_kernel<<<NB / 64, 256, 0, stream>>>(idx, w, pw);

    gather4_kernel<<<256, 1024, 131072, stream>>>(x, pw, out);
}